// Round 5
// baseline (601.496 us; speedup 1.0000x reference)
//
#include <hip/hip_runtime.h>
#include <math.h>

#define NF 1433
#define NH 16
#define NC 7
#define SCAN_BS 256
#define NCH 45          // ceil(1433/32), odd

typedef __attribute__((ext_vector_type(8))) short bf16x8;
typedef __attribute__((ext_vector_type(4))) float f32x4;

__device__ __forceinline__ unsigned short f2bf(float f) {
  unsigned int u = __float_as_uint(f);
  unsigned int r = (u + 0x7FFFu + ((u >> 16) & 1u)) >> 16;  // RNE
  return (unsigned short)r;
}
__device__ __forceinline__ unsigned int packbf(float lo, float hi) {
  return (unsigned int)f2bf(lo) | ((unsigned int)f2bf(hi) << 16);
}
// accumulate 8 bf16 (packed in uint4) into a[0..7]
__device__ __forceinline__ void acc8(float* a, uint4 r) {
  a[0] += __uint_as_float(r.x << 16); a[1] += __uint_as_float(r.x & 0xffff0000u);
  a[2] += __uint_as_float(r.y << 16); a[3] += __uint_as_float(r.y & 0xffff0000u);
  a[4] += __uint_as_float(r.z << 16); a[5] += __uint_as_float(r.z & 0xffff0000u);
  a[6] += __uint_as_float(r.w << 16); a[7] += __uint_as_float(r.w & 0xffff0000u);
}

// ---------------- CSR build (4-way sharded atomics, fused passes) ----------
__global__ void k_zero(int* __restrict__ p, int m) {
  int i = blockIdx.x * blockDim.x + threadIdx.x;
  if (i < m) p[i] = 0;
}

__global__ void k_count(const int* __restrict__ dst, int* __restrict__ cnt4, int E, int n) {
  int tid = blockIdx.x * blockDim.x + threadIdx.x;
  int stride = gridDim.x * blockDim.x;
  for (int e = tid * 4; e + 3 < E; e += stride * 4) {
    int4 d4 = *(const int4*)(dst + e);
    atomicAdd(&cnt4[d4.x], 1);
    atomicAdd(&cnt4[n + d4.y], 1);
    atomicAdd(&cnt4[2 * n + d4.z], 1);
    atomicAdd(&cnt4[3 * n + d4.w], 1);
  }
  if (tid == 0)
    for (int e = E & ~3; e < E; ++e) atomicAdd(&cnt4[(e & 3) * n + dst[e]], 1);
}

// block-scan of summed shard counts; also emits dis = rsqrt(deg+1)
__global__ void k_scan_block(const int* __restrict__ cnt4, int* __restrict__ off,
                             int* __restrict__ bsum, float* __restrict__ dis, int n) {
  __shared__ int sm[SCAN_BS];
  int t = threadIdx.x, i = blockIdx.x * SCAN_BS + t;
  int v = 0;
  if (i < n) {
    v = cnt4[i] + cnt4[n + i] + cnt4[2 * n + i] + cnt4[3 * n + i];
    dis[i] = rsqrtf((float)v + 1.0f);  // +1 = self loop
  }
  sm[t] = v;
  __syncthreads();
  for (int ofs = 1; ofs < SCAN_BS; ofs <<= 1) {
    int u = (t >= ofs) ? sm[t - ofs] : 0;
    __syncthreads();
    sm[t] += u;
    __syncthreads();
  }
  if (i < n) off[i] = sm[t] - v;
  if (t == SCAN_BS - 1) bsum[blockIdx.x] = sm[t];
}

__global__ void k_scan_bsum(const int* __restrict__ bsum, int* __restrict__ bofs,
                            int nb2, int* __restrict__ off, int n) {
  __shared__ int sm[512];
  int t = threadIdx.x;
  int v = (t < nb2) ? bsum[t] : 0;
  sm[t] = v;
  __syncthreads();
  for (int ofs = 1; ofs < 512; ofs <<= 1) {
    int u = (t >= ofs) ? sm[t - ofs] : 0;
    __syncthreads();
    sm[t] += u;
    __syncthreads();
  }
  if (t < nb2) bofs[t] = sm[t] - v;
  if (t == 511) off[n] = sm[511];
}

// finalize off, derive the 4 shard fill-pointers
__global__ void k_scan_add(int* __restrict__ off, const int* __restrict__ bofs,
                           const int* __restrict__ cnt4, int* __restrict__ ptr4, int n) {
  int i = blockIdx.x * SCAN_BS + threadIdx.x;
  if (i < n) {
    int o = off[i] + bofs[blockIdx.x];
    off[i] = o;
    ptr4[i] = o;              o += cnt4[i];
    ptr4[n + i] = o;          o += cnt4[n + i];
    ptr4[2 * n + i] = o;      o += cnt4[2 * n + i];
    ptr4[3 * n + i] = o;
  }
}

__global__ void k_fill(const int* __restrict__ ei, int* __restrict__ ptr4,
                       int* __restrict__ srcs, int E, int n) {
  const int* src = ei;
  const int* dst = ei + E;
  int tid = blockIdx.x * blockDim.x + threadIdx.x;
  int stride = gridDim.x * blockDim.x;
  for (int e = tid * 4; e + 3 < E; e += stride * 4) {
    int4 d4 = *(const int4*)(dst + e);
    int4 s4 = *(const int4*)(src + e);
    int p0 = atomicAdd(&ptr4[d4.x], 1);          srcs[p0] = s4.x;
    int p1 = atomicAdd(&ptr4[n + d4.y], 1);      srcs[p1] = s4.y;
    int p2 = atomicAdd(&ptr4[2 * n + d4.z], 1);  srcs[p2] = s4.z;
    int p3 = atomicAdd(&ptr4[3 * n + d4.w], 1);  srcs[p3] = s4.w;
  }
  if (tid == 0)
    for (int e = E & ~3; e < E; ++e) {
      int p = atomicAdd(&ptr4[(e & 3) * n + dst[e]], 1);
      srcs[p] = src[e];
    }
}

// scalar fallbacks (used only if E % 4 != 0; keeps int4 alignment safe)
__global__ void k_count_s(const int* __restrict__ dst, int* __restrict__ cnt4, int E, int n) {
  int stride = gridDim.x * blockDim.x;
  for (int e = blockIdx.x * blockDim.x + threadIdx.x; e < E; e += stride)
    atomicAdd(&cnt4[(e & 3) * n + dst[e]], 1);
}
__global__ void k_fill_s(const int* __restrict__ ei, int* __restrict__ ptr4,
                         int* __restrict__ srcs, int E, int n) {
  int stride = gridDim.x * blockDim.x;
  for (int e = blockIdx.x * blockDim.x + threadIdx.x; e < E; e += stride) {
    int p = atomicAdd(&ptr4[(e & 3) * n + ei[E + e]], 1);
    srcs[p] = ei[e];
  }
}

// ---------------- W1 -> per-chunk bf16 B-fragments ----------------
// Wb[(c*64 + lane)*8 + i] = bf16(W1[k][col]), k = c*32 + (lane>>4)*8 + i, col = lane&15
__global__ void k_wpack(const float* __restrict__ W1, short* __restrict__ Wb) {
  int t = blockIdx.x * blockDim.x + threadIdx.x;
  if (t >= NCH * 64 * 8) return;
  int i = t & 7, l = (t >> 3) & 63, c = t >> 9;
  int g = l >> 4, col = l & 15;
  int k = c * 32 + g * 8 + i;
  float v = (k < NF) ? W1[(size_t)k * NH + col] : 0.f;
  Wb[t] = (short)f2bf(v);
}

// ---------------- GEMM1 (MFMA bf16, no LDS, 2-deep prefetch) ----------------
// hs1 = bf16( (x @ W1) * dis[row] ), row layout [n][16] bf16 (32B rows)
__global__ __launch_bounds__(128) void k_gemm1(
    const float* __restrict__ x, const short* __restrict__ Wb,
    const float* __restrict__ dis, unsigned short* __restrict__ hs1, int n) {
  int l = threadIdx.x & 63;
  int row0 = blockIdx.x * 128 + (threadIdx.x >> 6) * 64;
  int rl = l & 15, g = l >> 4;

  const float* xp[4];
#pragma unroll
  for (int rt = 0; rt < 4; ++rt) {
    int r = row0 + rt * 16 + rl;
    int rc = r < n ? r : n - 1;  // clamp; garbage rows masked at store
    xp[rt] = x + (size_t)rc * NF + g * 8;
  }
  const bf16x8* wp = (const bf16x8*)Wb + l;

  f32x4 acc[4];
#pragma unroll
  for (int rt = 0; rt < 4; ++rt)
#pragma unroll
    for (int j = 0; j < 4; ++j) acc[rt][j] = 0.f;

  float xA[4][8], xB[4][8];  // named double buffers, static indexing only

#define LOADC(BUF, CB) { int _b = (CB) * 32;                         \
  _Pragma("unroll") for (int rt = 0; rt < 4; ++rt)                   \
  _Pragma("unroll") for (int i = 0; i < 8; ++i)                      \
    BUF[rt][i] = xp[rt][_b + i]; }

#define LOADCG(BUF, CB) { int _b = (CB) * 32;                        \
  _Pragma("unroll") for (int rt = 0; rt < 4; ++rt)                   \
  _Pragma("unroll") for (int i = 0; i < 8; ++i)                      \
    BUF[rt][i] = (_b + g * 8 + i < NF) ? xp[rt][_b + i] : 0.f; }

#define DOC(BUF, CC) { bf16x8 _w = wp[(size_t)(CC) * 64];            \
  _Pragma("unroll") for (int rt = 0; rt < 4; ++rt) { bf16x8 _a;      \
    _Pragma("unroll") for (int i = 0; i < 8; ++i)                    \
      _a[i] = (short)f2bf(BUF[rt][i]);                               \
    acc[rt] = __builtin_amdgcn_mfma_f32_16x16x32_bf16(_a, _w, acc[rt], 0, 0, 0); } }

  LOADC(xA, 0);
  LOADC(xB, 1);
  int c = 0;
  for (; c + 4 < NCH; c += 2) {
    DOC(xA, c);     LOADC(xA, c + 2);
    DOC(xB, c + 1); LOADC(xB, c + 3);
  }
  // here c == NCH-3 (odd NCH): chunks c, c+1, c+2 remain; c+2 is the guarded tail
  DOC(xA, c);     LOADCG(xA, c + 2);
  DOC(xB, c + 1);
  DOC(xA, c + 2);
#undef LOADC
#undef LOADCG
#undef DOC

  // D layout (m89): col = lane&15, row_in_tile = (lane>>4)*4 + reg
#pragma unroll
  for (int rt = 0; rt < 4; ++rt)
#pragma unroll
    for (int r = 0; r < 4; ++r) {
      int row = row0 + rt * 16 + g * 4 + r;
      if (row < n) hs1[(size_t)row * NH + rl] = f2bf(acc[rt][r] * dis[row]);
    }
}

// ---------------- pull layer 1 ----------------
// 8 lanes/node: bit0 = column half (8 bf16 = 16B), bits1-2 = edge phase (mod 4).
// v1 = relu(dis[d]*(hs1[d] + sum_in hs1[s]) + b1), f32 [n][16]
__global__ __launch_bounds__(256) void k_pull1(
    const int* __restrict__ off, const int* __restrict__ srcs,
    const float* __restrict__ dis, const uint4* __restrict__ hs1,
    const float* __restrict__ b1, float* __restrict__ v1, int n) {
  int t = blockIdx.x * blockDim.x + threadIdx.x;
  int d = t >> 3;
  if (d >= n) return;
  int sub = t & 7, half = sub & 1, ph = sub >> 1;

  float a[8] = {0.f, 0.f, 0.f, 0.f, 0.f, 0.f, 0.f, 0.f};
  if (ph == 0) acc8(a, hs1[(size_t)d * 2 + half]);  // self loop, once per half

  int k = off[d] + ph, k1 = off[d + 1];
  for (; k + 4 < k1; k += 8) {  // 2 independent gathers in flight
    int s0 = srcs[k], s1 = srcs[k + 4];
    uint4 r0 = hs1[(size_t)s0 * 2 + half];
    uint4 r1 = hs1[(size_t)s1 * 2 + half];
    acc8(a, r0);
    acc8(a, r1);
  }
  if (k < k1) acc8(a, hs1[(size_t)srcs[k] * 2 + half]);

#pragma unroll
  for (int i = 0; i < 8; ++i) {  // reduce over the 4 phases (lanes differing in bits 1,2)
    a[i] += __shfl_xor(a[i], 2);
    a[i] += __shfl_xor(a[i], 4);
  }
  if (ph == 0) {
    float dd = dis[d];
    const float* bb = b1 + half * 8;
    float4 o0, o1;
    o0.x = fmaxf(a[0] * dd + bb[0], 0.f);
    o0.y = fmaxf(a[1] * dd + bb[1], 0.f);
    o0.z = fmaxf(a[2] * dd + bb[2], 0.f);
    o0.w = fmaxf(a[3] * dd + bb[3], 0.f);
    o1.x = fmaxf(a[4] * dd + bb[4], 0.f);
    o1.y = fmaxf(a[5] * dd + bb[5], 0.f);
    o1.z = fmaxf(a[6] * dd + bb[6], 0.f);
    o1.w = fmaxf(a[7] * dd + bb[7], 0.f);
    float4* vp = (float4*)(v1 + (size_t)d * NH + half * 8);
    vp[0] = o0;
    vp[1] = o1;
  }
}

// ---------------- GEMM2: hs2 = bf16( (v1 @ W2) * dis ), [n][8] bf16 (16B rows)
__global__ void k_gemm2(const float* __restrict__ v1, const float* __restrict__ W2,
                        const float* __restrict__ dis, uint4* __restrict__ hs2, int n) {
  int i = blockIdx.x * blockDim.x + threadIdx.x;
  if (i >= n) return;
  float v[NH];
  const float4* a4 = (const float4*)(v1 + (size_t)i * NH);
#pragma unroll
  for (int jj = 0; jj < 4; ++jj) {
    float4 tv = a4[jj];
    v[jj * 4 + 0] = tv.x; v[jj * 4 + 1] = tv.y;
    v[jj * 4 + 2] = tv.z; v[jj * 4 + 3] = tv.w;
  }
  float d = dis[i];
  float s[8];
#pragma unroll
  for (int c = 0; c < NC; ++c) {
    float t = 0.f;
#pragma unroll
    for (int j = 0; j < NH; ++j) t = fmaf(v[j], W2[j * NC + c], t);
    s[c] = t * d;
  }
  s[7] = 0.f;  // pad column
  uint4 o;
  o.x = packbf(s[0], s[1]);
  o.y = packbf(s[2], s[3]);
  o.z = packbf(s[4], s[5]);
  o.w = packbf(s[6], s[7]);
  hs2[i] = o;
}

// ---------------- pull layer 2 + bias + relu + log_softmax ----------------
// 4 lanes/node, each lane = one edge phase (mod 4), reads the full 16B row.
__global__ __launch_bounds__(256) void k_pull2(
    const int* __restrict__ off, const int* __restrict__ srcs,
    const float* __restrict__ dis, const uint4* __restrict__ hs2,
    const float* __restrict__ b2, float* __restrict__ out, int n) {
  int t = blockIdx.x * blockDim.x + threadIdx.x;
  int d = t >> 2;
  if (d >= n) return;
  int ph = t & 3;

  float a[8] = {0.f, 0.f, 0.f, 0.f, 0.f, 0.f, 0.f, 0.f};
  if (ph == 0) acc8(a, hs2[d]);  // self loop once

  int k = off[d] + ph, k1 = off[d + 1];
  for (; k + 4 < k1; k += 8) {
    int s0 = srcs[k], s1 = srcs[k + 4];
    uint4 r0 = hs2[s0];
    uint4 r1 = hs2[s1];
    acc8(a, r0);
    acc8(a, r1);
  }
  if (k < k1) acc8(a, hs2[srcs[k]]);

#pragma unroll
  for (int i = 0; i < 8; ++i) {  // reduce across the 4 phase lanes
    a[i] += __shfl_xor(a[i], 1);
    a[i] += __shfl_xor(a[i], 2);
  }
  float dd = dis[d];
  float u[NC];
#pragma unroll
  for (int c = 0; c < NC; ++c) u[c] = fmaxf(a[c] * dd + b2[c], 0.f);
  float m = u[0];
#pragma unroll
  for (int c = 1; c < NC; ++c) m = fmaxf(m, u[c]);
  float sum = 0.f;
#pragma unroll
  for (int c = 0; c < NC; ++c) sum += expf(u[c] - m);
  float lg = logf(sum);
  out[(size_t)d * NC + ph] = u[ph] - m - lg;
  if (ph + 4 < NC) out[(size_t)d * NC + ph + 4] = u[ph + 4] - m - lg;
}

extern "C" void kernel_launch(void* const* d_in, const int* in_sizes, int n_in,
                              void* d_out, int out_size, void* d_ws, size_t ws_size,
                              hipStream_t stream) {
  const float* x  = (const float*)d_in[0];
  const int*   ei = (const int*)d_in[1];
  const float* W1 = (const float*)d_in[2];
  const float* b1 = (const float*)d_in[3];
  const float* W2 = (const float*)d_in[4];
  const float* b2 = (const float*)d_in[5];
  int n = in_sizes[0] / NF;   // 100000
  int E = in_sizes[1] / 2;    // 3200000

  // workspace layout (each region 16B-aligned)
  char* w = (char*)d_ws;
#define TAKE(ptrty, name, bytes) \
  ptrty name = (ptrty)w; w += ((size_t)(bytes) + 15) & ~(size_t)15;
  TAKE(unsigned short*, hs1, sizeof(short) * (size_t)n * NH)
  TAKE(uint4*,          hs2, 16 * (size_t)n)
  TAKE(float*,          v1,  sizeof(float) * (size_t)n * NH)
  TAKE(float*,          dis, sizeof(float) * n)
  TAKE(short*,          Wb,  sizeof(short) * NCH * 64 * 8)
  TAKE(int*,            cnt4, sizeof(int) * 4 * (size_t)n)
  TAKE(int*,            ptr4, sizeof(int) * 4 * (size_t)n)
  TAKE(int*,            off,  sizeof(int) * (n + 1))
  TAKE(int*,            srcs, sizeof(int) * (size_t)E)
  TAKE(int*,            bsum, sizeof(int) * 512)
  TAKE(int*,            bofs, sizeof(int) * 512)
#undef TAKE
  float* out = (float*)d_out;

  int nb = (n + 255) / 256;
  int nscan = (n + SCAN_BS - 1) / SCAN_BS;   // 391 <= 512

  // CSR build
  k_zero<<<(4 * n + 255) / 256, 256, 0, stream>>>(cnt4, 4 * n);
  if ((E & 3) == 0) {
    k_count<<<2048, 256, 0, stream>>>(ei + E, cnt4, E, n);
  } else {
    k_count_s<<<2048, 256, 0, stream>>>(ei + E, cnt4, E, n);
  }
  k_scan_block<<<nscan, SCAN_BS, 0, stream>>>(cnt4, off, bsum, dis, n);
  k_scan_bsum<<<1, 512, 0, stream>>>(bsum, bofs, nscan, off, n);
  k_scan_add<<<nscan, SCAN_BS, 0, stream>>>(off, bofs, cnt4, ptr4, n);
  if ((E & 3) == 0) {
    k_fill<<<2048, 256, 0, stream>>>(ei, ptr4, srcs, E, n);
  } else {
    k_fill_s<<<2048, 256, 0, stream>>>(ei, ptr4, srcs, E, n);
  }

  // features
  k_wpack<<<(NCH * 64 * 8 + 255) / 256, 256, 0, stream>>>(W1, Wb);
  k_gemm1<<<(n + 127) / 128, 128, 0, stream>>>(x, Wb, dis, hs1, n);
  k_pull1<<<((size_t)n * 8 + 255) / 256, 256, 0, stream>>>(off, srcs, dis,
                                                           (const uint4*)hs1, b1, v1, n);
  k_gemm2<<<nb, 256, 0, stream>>>(v1, W2, dis, hs2, n);
  k_pull2<<<((size_t)n * 4 + 255) / 256, 256, 0, stream>>>(off, srcs, dis,
                                                           hs2, b2, out, n);
}

// Round 6
// 365.833 us; speedup vs baseline: 1.6442x; 1.6442x over previous
//
#include <hip/hip_runtime.h>
#include <math.h>

#define NF 1433
#define NH 16
#define NC 7
#define NCH 45          // ceil(1433/32), odd
#define NBKT_MAX 512    // supports n <= 131072 (bucket = dst>>8)
#define EBLK 1024       // edge-pass blocks

typedef __attribute__((ext_vector_type(8))) short bf16x8;
typedef __attribute__((ext_vector_type(4))) float f32x4;

__device__ __forceinline__ unsigned short f2bf(float f) {
  unsigned int u = __float_as_uint(f);
  unsigned int r = (u + 0x7FFFu + ((u >> 16) & 1u)) >> 16;  // RNE
  return (unsigned short)r;
}
__device__ __forceinline__ unsigned int packbf(float lo, float hi) {
  return (unsigned int)f2bf(lo) | ((unsigned int)f2bf(hi) << 16);
}
// accumulate 8 bf16 (packed in uint4) into a[0..7]
__device__ __forceinline__ void acc8(float* a, uint4 r) {
  a[0] += __uint_as_float(r.x << 16); a[1] += __uint_as_float(r.x & 0xffff0000u);
  a[2] += __uint_as_float(r.y << 16); a[3] += __uint_as_float(r.y & 0xffff0000u);
  a[4] += __uint_as_float(r.z << 16); a[5] += __uint_as_float(r.z & 0xffff0000u);
  a[6] += __uint_as_float(r.w << 16); a[7] += __uint_as_float(r.w & 0xffff0000u);
}

// ---------------- bucketed CSR build ----------------
// bcnt/bfill are line-padded (stride 16 ints = 64B) to keep per-counter
// atomic serialization on independent cache lines.

__global__ void k_zero(int* __restrict__ p, int m) {
  int i = blockIdx.x * blockDim.x + threadIdx.x;
  if (i < m) p[i] = 0;
}

// pass A1: per-block LDS histogram of dst>>8, flush via line-padded atomics
__global__ __launch_bounds__(256) void k_bcount(const int* __restrict__ dst,
                                                int* __restrict__ bcnt,
                                                int E, int nbkt, int chunk) {
  __shared__ int h[NBKT_MAX];
  int t = threadIdx.x;
  for (int i = t; i < nbkt; i += 256) h[i] = 0;
  __syncthreads();
  int e0 = blockIdx.x * chunk;
  int e1 = min(E, e0 + chunk);
  for (int e = e0 + t; e < e1; e += 256)
    atomicAdd(&h[((unsigned)dst[e]) >> 8], 1);
  __syncthreads();
  for (int i = t; i < nbkt; i += 256)
    if (h[i]) atomicAdd(&bcnt[i * 16], h[i]);
}

// pass A2: single-block exclusive scan of bucket sizes -> bbase; init bfill
__global__ void k_bscan(const int* __restrict__ bcnt, int* __restrict__ bbase,
                        int* __restrict__ bfill, int nbkt) {
  __shared__ int sm[NBKT_MAX];
  int t = threadIdx.x;  // blockDim = NBKT_MAX
  int v = (t < nbkt) ? bcnt[t * 16] : 0;
  sm[t] = v;
  __syncthreads();
  for (int o = 1; o < NBKT_MAX; o <<= 1) {
    int u = (t >= o) ? sm[t - o] : 0;
    __syncthreads();
    sm[t] += u;
    __syncthreads();
  }
  if (t < nbkt) {
    int b = sm[t] - v;
    bbase[t] = b;
    bfill[t * 16] = b;
  }
  if (t == nbkt) bbase[nbkt] = sm[t];  // == E (entries past nbkt-1 are 0)
}

// pass A3: reserve per-(block,bucket) slot ranges (1 global atomic each),
// then scatter packed (dstLow<<24)|src into bucket regions via LDS cursors
__global__ __launch_bounds__(256) void k_bscatter(const int* __restrict__ ei,
                                                  int* __restrict__ bfill,
                                                  int* __restrict__ ebuf,
                                                  int E, int nbkt, int chunk) {
  __shared__ int h[NBKT_MAX];
  __shared__ int lb[NBKT_MAX];
  const int* src = ei;
  const int* dst = ei + E;
  int t = threadIdx.x;
  for (int i = t; i < nbkt; i += 256) h[i] = 0;
  __syncthreads();
  int e0 = blockIdx.x * chunk;
  int e1 = min(E, e0 + chunk);
  for (int e = e0 + t; e < e1; e += 256)
    atomicAdd(&h[((unsigned)dst[e]) >> 8], 1);
  __syncthreads();
  for (int i = t; i < nbkt; i += 256) {
    int c = h[i];
    lb[i] = c ? atomicAdd(&bfill[i * 16], c) : 0;
    h[i] = 0;  // reuse as local cursor
  }
  __syncthreads();
  for (int e = e0 + t; e < e1; e += 256) {
    unsigned d = (unsigned)dst[e];
    int bk = d >> 8;
    int idx = atomicAdd(&h[bk], 1);
    ebuf[lb[bk] + idx] = (int)(((d & 255u) << 24) | (unsigned)src[e]);
  }
}

// pass B: one workgroup per bucket -> local CSR (off, srcs) + dis, all LDS-local
__global__ __launch_bounds__(256) void k_bcsr(const int* __restrict__ ebuf,
                                              const int* __restrict__ bbase,
                                              int* __restrict__ off,
                                              int* __restrict__ srcs,
                                              float* __restrict__ dis, int n) {
  __shared__ int h[256];
  __shared__ int sc[256];
  int b = blockIdx.x, t = threadIdx.x;
  int eb = bbase[b], ee = bbase[b + 1];
  h[t] = 0;
  __syncthreads();
  for (int i = eb + t; i < ee; i += 256)
    atomicAdd(&h[((unsigned)ebuf[i]) >> 24], 1);
  __syncthreads();
  int deg = h[t];
  sc[t] = deg;
  __syncthreads();
  for (int o = 1; o < 256; o <<= 1) {
    int u = (t >= o) ? sc[t - o] : 0;
    __syncthreads();
    sc[t] += u;
    __syncthreads();
  }
  int excl = sc[t] - deg;
  int node = (b << 8) + t;
  if (node < n) {
    off[node] = eb + excl;
    dis[node] = rsqrtf((float)deg + 1.0f);
  }
  if (b == (int)gridDim.x - 1 && t == 0) off[n] = ee;  // == E
  h[t] = eb + excl;  // reuse as fill cursor
  __syncthreads();
  for (int i = eb + t; i < ee; i += 256) {
    unsigned v = (unsigned)ebuf[i];
    int slot = atomicAdd(&h[v >> 24], 1);
    srcs[slot] = (int)(v & 0xFFFFFFu);
  }
}

// ---------------- W1 -> per-chunk bf16 B-fragments ----------------
// Wb[(c*64 + lane)*8 + i] = bf16(W1[k][col]), k = c*32 + (lane>>4)*8 + i, col = lane&15
__global__ void k_wpack(const float* __restrict__ W1, short* __restrict__ Wb) {
  int t = blockIdx.x * blockDim.x + threadIdx.x;
  if (t >= NCH * 64 * 8) return;
  int i = t & 7, l = (t >> 3) & 63, c = t >> 9;
  int g = l >> 4, col = l & 15;
  int k = c * 32 + g * 8 + i;
  float v = (k < NF) ? W1[(size_t)k * NH + col] : 0.f;
  Wb[t] = (short)f2bf(v);
}

// ---------------- GEMM1 (MFMA bf16, no LDS, 2-deep prefetch) ----------------
// hs1 = bf16( (x @ W1) * dis[row] ), row layout [n][16] bf16 (32B rows)
__global__ __launch_bounds__(128) void k_gemm1(
    const float* __restrict__ x, const short* __restrict__ Wb,
    const float* __restrict__ dis, unsigned short* __restrict__ hs1, int n) {
  int l = threadIdx.x & 63;
  int row0 = blockIdx.x * 128 + (threadIdx.x >> 6) * 64;
  int rl = l & 15, g = l >> 4;

  const float* xp[4];
#pragma unroll
  for (int rt = 0; rt < 4; ++rt) {
    int r = row0 + rt * 16 + rl;
    int rc = r < n ? r : n - 1;  // clamp; garbage rows masked at store
    xp[rt] = x + (size_t)rc * NF + g * 8;
  }
  const bf16x8* wp = (const bf16x8*)Wb + l;

  f32x4 acc[4];
#pragma unroll
  for (int rt = 0; rt < 4; ++rt)
#pragma unroll
    for (int j = 0; j < 4; ++j) acc[rt][j] = 0.f;

  float xA[4][8], xB[4][8];  // named double buffers, static indexing only

#define LOADC(BUF, CB) { int _b = (CB) * 32;                         \
  _Pragma("unroll") for (int rt = 0; rt < 4; ++rt)                   \
  _Pragma("unroll") for (int i = 0; i < 8; ++i)                      \
    BUF[rt][i] = xp[rt][_b + i]; }

#define LOADCG(BUF, CB) { int _b = (CB) * 32;                        \
  _Pragma("unroll") for (int rt = 0; rt < 4; ++rt)                   \
  _Pragma("unroll") for (int i = 0; i < 8; ++i)                      \
    BUF[rt][i] = (_b + g * 8 + i < NF) ? xp[rt][_b + i] : 0.f; }

#define DOC(BUF, CC) { bf16x8 _w = wp[(size_t)(CC) * 64];            \
  _Pragma("unroll") for (int rt = 0; rt < 4; ++rt) { bf16x8 _a;      \
    _Pragma("unroll") for (int i = 0; i < 8; ++i)                    \
      _a[i] = (short)f2bf(BUF[rt][i]);                               \
    acc[rt] = __builtin_amdgcn_mfma_f32_16x16x32_bf16(_a, _w, acc[rt], 0, 0, 0); } }

  LOADC(xA, 0);
  LOADC(xB, 1);
  int c = 0;
  for (; c + 4 < NCH; c += 2) {
    DOC(xA, c);     LOADC(xA, c + 2);
    DOC(xB, c + 1); LOADC(xB, c + 3);
  }
  // c == NCH-3 (odd NCH): chunks c, c+1, c+2 remain; c+2 is the guarded tail
  DOC(xA, c);     LOADCG(xA, c + 2);
  DOC(xB, c + 1);
  DOC(xA, c + 2);
#undef LOADC
#undef LOADCG
#undef DOC

  // D layout (m89): col = lane&15, row_in_tile = (lane>>4)*4 + reg
#pragma unroll
  for (int rt = 0; rt < 4; ++rt)
#pragma unroll
    for (int r = 0; r < 4; ++r) {
      int row = row0 + rt * 16 + g * 4 + r;
      if (row < n) hs1[(size_t)row * NH + rl] = f2bf(acc[rt][r] * dis[row]);
    }
}

// ---------------- pull layer 1 + bias + relu + GEMM2 fused ----------------
// 8 lanes/node: bit0 = column half (8 bf16 = 16B), bits1-2 = edge phase.
// After the xor-butterfly ALL lanes hold their half's sums; each half-lane
// computes its 8x7 partial matvec with W2, shfl_xor(1) combines halves, and
// lane sub==0 writes hs2 = bf16((relu(agg*dis+b1) @ W2) * dis), [n][8] bf16.
__global__ __launch_bounds__(256) void k_pull1(
    const int* __restrict__ off, const int* __restrict__ srcs,
    const float* __restrict__ dis, const uint4* __restrict__ hs1,
    const float* __restrict__ b1, const float* __restrict__ W2,
    uint4* __restrict__ hs2, int n) {
  int t = blockIdx.x * blockDim.x + threadIdx.x;
  int d = t >> 3;
  if (d >= n) return;
  int sub = t & 7, half = sub & 1, ph = sub >> 1;

  float a[8] = {0.f, 0.f, 0.f, 0.f, 0.f, 0.f, 0.f, 0.f};
  if (ph == 0) acc8(a, hs1[(size_t)d * 2 + half]);  // self loop, once per half

  int k = off[d] + ph, k1 = off[d + 1];
  for (; k + 4 < k1; k += 8) {  // 2 independent gathers in flight
    int s0 = srcs[k], s1 = srcs[k + 4];
    uint4 r0 = hs1[(size_t)s0 * 2 + half];
    uint4 r1 = hs1[(size_t)s1 * 2 + half];
    acc8(a, r0);
    acc8(a, r1);
  }
  if (k < k1) acc8(a, hs1[(size_t)srcs[k] * 2 + half]);

#pragma unroll
  for (int i = 0; i < 8; ++i) {  // reduce over the 4 phases (lane bits 1,2)
    a[i] += __shfl_xor(a[i], 2);
    a[i] += __shfl_xor(a[i], 4);
  }

  // fused epilogue (all lanes): v = relu(a*dis + b1[half*8 + i])
  float dd = dis[d];
  float v[8];
#pragma unroll
  for (int i = 0; i < 8; ++i) v[i] = fmaxf(a[i] * dd + b1[half * 8 + i], 0.f);
  float p[NC];
#pragma unroll
  for (int c = 0; c < NC; ++c) {
    float s = 0.f;
#pragma unroll
    for (int i = 0; i < 8; ++i) s = fmaf(v[i], W2[(half * 8 + i) * NC + c], s);
    p[c] = s;
  }
#pragma unroll
  for (int c = 0; c < NC; ++c) p[c] += __shfl_xor(p[c], 1);  // combine halves
  if (sub == 0) {
    uint4 o;
    o.x = packbf(p[0] * dd, p[1] * dd);
    o.y = packbf(p[2] * dd, p[3] * dd);
    o.z = packbf(p[4] * dd, p[5] * dd);
    o.w = packbf(p[6] * dd, 0.f);  // pad col
    hs2[d] = o;
  }
}

// ---------------- pull layer 2 + bias + relu + log_softmax ----------------
// 4 lanes/node, each lane = one edge phase (mod 4), reads the full 16B row.
__global__ __launch_bounds__(256) void k_pull2(
    const int* __restrict__ off, const int* __restrict__ srcs,
    const float* __restrict__ dis, const uint4* __restrict__ hs2,
    const float* __restrict__ b2, float* __restrict__ out, int n) {
  int t = blockIdx.x * blockDim.x + threadIdx.x;
  int d = t >> 2;
  if (d >= n) return;
  int ph = t & 3;

  float a[8] = {0.f, 0.f, 0.f, 0.f, 0.f, 0.f, 0.f, 0.f};
  if (ph == 0) acc8(a, hs2[d]);  // self loop once

  int k = off[d] + ph, k1 = off[d + 1];
  for (; k + 4 < k1; k += 8) {
    int s0 = srcs[k], s1 = srcs[k + 4];
    uint4 r0 = hs2[s0];
    uint4 r1 = hs2[s1];
    acc8(a, r0);
    acc8(a, r1);
  }
  if (k < k1) acc8(a, hs2[srcs[k]]);

#pragma unroll
  for (int i = 0; i < 8; ++i) {  // reduce across the 4 phase lanes
    a[i] += __shfl_xor(a[i], 1);
    a[i] += __shfl_xor(a[i], 2);
  }
  float dd = dis[d];
  float u[NC];
#pragma unroll
  for (int c = 0; c < NC; ++c) u[c] = fmaxf(a[c] * dd + b2[c], 0.f);
  float m = u[0];
#pragma unroll
  for (int c = 1; c < NC; ++c) m = fmaxf(m, u[c]);
  float sum = 0.f;
#pragma unroll
  for (int c = 0; c < NC; ++c) sum += expf(u[c] - m);
  float lg = logf(sum);
  out[(size_t)d * NC + ph] = u[ph] - m - lg;
  if (ph + 4 < NC) out[(size_t)d * NC + ph + 4] = u[ph + 4] - m - lg;
}

extern "C" void kernel_launch(void* const* d_in, const int* in_sizes, int n_in,
                              void* d_out, int out_size, void* d_ws, size_t ws_size,
                              hipStream_t stream) {
  const float* x  = (const float*)d_in[0];
  const int*   ei = (const int*)d_in[1];
  const float* W1 = (const float*)d_in[2];
  const float* b1 = (const float*)d_in[3];
  const float* W2 = (const float*)d_in[4];
  const float* b2 = (const float*)d_in[5];
  int n = in_sizes[0] / NF;   // 100000
  int E = in_sizes[1] / 2;    // 3200000
  int nbkt = (n + 255) >> 8;  // 391

  // workspace layout (each region 16B-aligned)
  char* w = (char*)d_ws;
#define TAKE(ptrty, name, bytes) \
  ptrty name = (ptrty)w; w += ((size_t)(bytes) + 15) & ~(size_t)15;
  TAKE(unsigned short*, hs1,  sizeof(short) * (size_t)n * NH)
  TAKE(uint4*,          hs2,  16 * (size_t)n)
  TAKE(float*,          dis,  sizeof(float) * n)
  TAKE(short*,          Wb,   sizeof(short) * NCH * 64 * 8)
  TAKE(int*,            bcnt, sizeof(int) * 16 * NBKT_MAX)
  TAKE(int*,            bfill,sizeof(int) * 16 * NBKT_MAX)
  TAKE(int*,            bbase,sizeof(int) * (NBKT_MAX + 1))
  TAKE(int*,            ebuf, sizeof(int) * (size_t)E)
  TAKE(int*,            off,  sizeof(int) * (n + 1))
  TAKE(int*,            srcs, sizeof(int) * (size_t)E)
#undef TAKE
  float* out = (float*)d_out;

  int chunk = (E + EBLK - 1) / EBLK;

  // bucketed CSR build
  k_zero<<<(16 * NBKT_MAX + 255) / 256, 256, 0, stream>>>(bcnt, 16 * NBKT_MAX);
  k_bcount<<<EBLK, 256, 0, stream>>>(ei + E, bcnt, E, nbkt, chunk);
  k_bscan<<<1, NBKT_MAX, 0, stream>>>(bcnt, bbase, bfill, nbkt);
  k_bscatter<<<EBLK, 256, 0, stream>>>(ei, bfill, ebuf, E, nbkt, chunk);
  k_bcsr<<<nbkt, 256, 0, stream>>>(ebuf, bbase, off, srcs, dis, n);

  // features
  k_wpack<<<(NCH * 64 * 8 + 255) / 256, 256, 0, stream>>>(W1, Wb);
  k_gemm1<<<(n + 127) / 128, 128, 0, stream>>>(x, Wb, dis, hs1, n);
  k_pull1<<<((size_t)n * 8 + 255) / 256, 256, 0, stream>>>(
      off, srcs, dis, (const uint4*)hs1, b1, W2, hs2, n);
  k_pull2<<<((size_t)n * 4 + 255) / 256, 256, 0, stream>>>(
      off, srcs, dis, hs2, b2, out, n);
}

// Round 7
// 323.016 us; speedup vs baseline: 1.8621x; 1.1326x over previous
//
#include <hip/hip_runtime.h>
#include <math.h>

#define NF 1433
#define NH 16
#define NC 7
#define NCH 45          // ceil(1433/32), odd
#define NBKT_MAX 512    // supports n <= 131072 (bucket = dst>>8)
#define SC_C 3072       // edges per bscatter block (LDS-sortable chunk)

typedef __attribute__((ext_vector_type(8))) short bf16x8;
typedef __attribute__((ext_vector_type(4))) float f32x4;

__device__ __forceinline__ unsigned short f2bf(float f) {
  unsigned int u = __float_as_uint(f);
  unsigned int r = (u + 0x7FFFu + ((u >> 16) & 1u)) >> 16;  // RNE
  return (unsigned short)r;
}
__device__ __forceinline__ unsigned int packbf(float lo, float hi) {
  return (unsigned int)f2bf(lo) | ((unsigned int)f2bf(hi) << 16);
}
// accumulate 8 bf16 (packed in uint4) into a[0..7]
__device__ __forceinline__ void acc8(float* a, uint4 r) {
  a[0] += __uint_as_float(r.x << 16); a[1] += __uint_as_float(r.x & 0xffff0000u);
  a[2] += __uint_as_float(r.y << 16); a[3] += __uint_as_float(r.y & 0xffff0000u);
  a[4] += __uint_as_float(r.z << 16); a[5] += __uint_as_float(r.z & 0xffff0000u);
  a[6] += __uint_as_float(r.w << 16); a[7] += __uint_as_float(r.w & 0xffff0000u);
}

// ---------------- W1 fragment pack + bcnt zero (fused, independent work) ----
// Wb[(c*64 + lane)*8 + i] = bf16(W1[k][col]), k = c*32 + (lane>>4)*8 + i, col = lane&15
__global__ void k_wpack_zero(const float* __restrict__ W1, short* __restrict__ Wb,
                             int* __restrict__ bcnt) {
  int t = blockIdx.x * blockDim.x + threadIdx.x;
  if (t < 16 * NBKT_MAX) bcnt[t] = 0;
  if (t >= NCH * 64 * 8) return;
  int i = t & 7, l = (t >> 3) & 63, c = t >> 9;
  int g = l >> 4, col = l & 15;
  int k = c * 32 + g * 8 + i;
  float v = (k < NF) ? W1[(size_t)k * NH + col] : 0.f;
  Wb[t] = (short)f2bf(v);
}

// ---------------- bucketed CSR build ----------------
// pass A1: per-block LDS histogram of dst>>8, flush via line-padded atomics
__global__ __launch_bounds__(256) void k_bcount(const int* __restrict__ dst,
                                                int* __restrict__ bcnt,
                                                int E, int nbkt) {
  __shared__ int h[NBKT_MAX];
  int t = threadIdx.x;
  for (int i = t; i < nbkt; i += 256) h[i] = 0;
  __syncthreads();
  int e0 = blockIdx.x * SC_C;
  int e1 = min(E, e0 + SC_C);
  for (int e = e0 + t; e < e1; e += 256)
    atomicAdd(&h[((unsigned)dst[e]) >> 8], 1);
  __syncthreads();
  for (int i = t; i < nbkt; i += 256)
    if (h[i]) atomicAdd(&bcnt[i * 16], h[i]);
}

// pass A2: single-block exclusive scan of bucket sizes -> bbase; init bfill
__global__ void k_bscan(const int* __restrict__ bcnt, int* __restrict__ bbase,
                        int* __restrict__ bfill, int nbkt) {
  __shared__ int sm[NBKT_MAX];
  int t = threadIdx.x;  // blockDim = NBKT_MAX
  int v = (t < nbkt) ? bcnt[t * 16] : 0;
  sm[t] = v;
  __syncthreads();
  for (int o = 1; o < NBKT_MAX; o <<= 1) {
    int u = (t >= o) ? sm[t - o] : 0;
    __syncthreads();
    sm[t] += u;
    __syncthreads();
  }
  if (t < nbkt) {
    int b = sm[t] - v;
    bbase[t] = b;
    bfill[t * 16] = b;
  }
  if (t == nbkt) bbase[nbkt] = sm[t];  // == E
}

// pass A3 (radix-partition): hist -> local scan -> LDS bucket-sort of the
// chunk -> coalesced run writes. One global atomic per (block,bucket).
__global__ __launch_bounds__(256) void k_bscatter(const int* __restrict__ ei,
                                                  int* __restrict__ bfill,
                                                  int* __restrict__ ebuf,
                                                  int E, int nbkt) {
  __shared__ int h[NBKT_MAX];              // hist, then fill cursor
  __shared__ int lo[NBKT_MAX];             // block-local exclusive base
  __shared__ int lb[NBKT_MAX];             // reserved global base
  __shared__ int sc2[256];
  __shared__ int sval[SC_C];
  __shared__ unsigned short sbkt[SC_C];
  const int* src = ei;
  const int* dst = ei + E;
  int t = threadIdx.x;
  for (int i = t; i < NBKT_MAX; i += 256) h[i] = 0;
  __syncthreads();
  int e0 = blockIdx.x * SC_C;
  int e1 = min(E, e0 + SC_C);
  int csize = e1 - e0;
  for (int e = e0 + t; e < e1; e += 256)
    atomicAdd(&h[((unsigned)dst[e]) >> 8], 1);
  __syncthreads();
  // exclusive scan of h[0..512) -> lo (two 256-wide passes)
  int base = 0;
#pragma unroll
  for (int j = 0; j < 2; ++j) {
    int idx = j * 256 + t;
    int v = h[idx];
    sc2[t] = v;
    __syncthreads();
    for (int o = 1; o < 256; o <<= 1) {
      int u = (t >= o) ? sc2[t - o] : 0;
      __syncthreads();
      sc2[t] += u;
      __syncthreads();
    }
    lo[idx] = base + sc2[t] - v;
    int tot = sc2[255];
    __syncthreads();
    base += tot;
  }
  // reserve global ranges, reset cursors
  for (int i = t; i < nbkt; i += 256) {
    int c = h[i];
    lb[i] = c ? atomicAdd(&bfill[i * 16], c) : 0;
    h[i] = 0;
  }
  __syncthreads();
  // sort chunk into LDS by bucket
  for (int e = e0 + t; e < e1; e += 256) {
    unsigned d = (unsigned)dst[e];
    int bk = d >> 8;
    int p = lo[bk] + atomicAdd(&h[bk], 1);
    sval[p] = (int)(((d & 255u) << 24) | (unsigned)src[e]);
    sbkt[p] = (unsigned short)bk;
  }
  __syncthreads();
  // coalesced run writes: consecutive i -> consecutive dest within a run
  for (int i = t; i < csize; i += 256) {
    int bk = sbkt[i];
    ebuf[lb[bk] + (i - lo[bk])] = sval[i];
  }
}

// pass B: one workgroup per bucket -> local CSR (off, srcs) + dis, LDS-local
__global__ __launch_bounds__(256) void k_bcsr(const int* __restrict__ ebuf,
                                              const int* __restrict__ bbase,
                                              int* __restrict__ off,
                                              int* __restrict__ srcs,
                                              float* __restrict__ dis, int n) {
  __shared__ int h[256];
  __shared__ int sc[256];
  int b = blockIdx.x, t = threadIdx.x;
  int eb = bbase[b], ee = bbase[b + 1];
  h[t] = 0;
  __syncthreads();
  for (int i = eb + t; i < ee; i += 256)
    atomicAdd(&h[((unsigned)ebuf[i]) >> 24], 1);
  __syncthreads();
  int deg = h[t];
  sc[t] = deg;
  __syncthreads();
  for (int o = 1; o < 256; o <<= 1) {
    int u = (t >= o) ? sc[t - o] : 0;
    __syncthreads();
    sc[t] += u;
    __syncthreads();
  }
  int excl = sc[t] - deg;
  int node = (b << 8) + t;
  if (node < n) {
    off[node] = eb + excl;
    dis[node] = rsqrtf((float)deg + 1.0f);
  }
  if (b == (int)gridDim.x - 1 && t == 0) off[n] = ee;
  h[t] = eb + excl;  // reuse as fill cursor
  __syncthreads();
  for (int i = eb + t; i < ee; i += 256) {
    unsigned v = (unsigned)ebuf[i];
    int slot = atomicAdd(&h[v >> 24], 1);
    srcs[slot] = (int)(v & 0xFFFFFFu);
  }
}

// ---------------- GEMM1 (MFMA bf16, no LDS, 2-deep prefetch, 2 tiles/wave) --
// hs1 = bf16( (x @ W1) * dis[row] ), row layout [n][16] bf16 (32B rows)
__global__ __launch_bounds__(128) void k_gemm1(
    const float* __restrict__ x, const short* __restrict__ Wb,
    const float* __restrict__ dis, unsigned short* __restrict__ hs1, int n) {
  int l = threadIdx.x & 63;
  int row0 = blockIdx.x * 64 + (threadIdx.x >> 6) * 32;  // wave = 32 rows
  int rl = l & 15, g = l >> 4;

  const float* xp[2];
#pragma unroll
  for (int rt = 0; rt < 2; ++rt) {
    int r = row0 + rt * 16 + rl;
    int rc = r < n ? r : n - 1;  // clamp; masked at store
    xp[rt] = x + (size_t)rc * NF + g * 8;
  }
  const bf16x8* wp = (const bf16x8*)Wb + l;

  f32x4 acc[2];
#pragma unroll
  for (int rt = 0; rt < 2; ++rt)
#pragma unroll
    for (int j = 0; j < 4; ++j) acc[rt][j] = 0.f;

  float xA[2][8], xB[2][8];  // named double buffers, static indexing only

#define LOADC(BUF, CB) { int _b = (CB) * 32;                         \
  _Pragma("unroll") for (int rt = 0; rt < 2; ++rt)                   \
  _Pragma("unroll") for (int i = 0; i < 8; ++i)                      \
    BUF[rt][i] = xp[rt][_b + i]; }

#define LOADCG(BUF, CB) { int _b = (CB) * 32;                        \
  _Pragma("unroll") for (int rt = 0; rt < 2; ++rt)                   \
  _Pragma("unroll") for (int i = 0; i < 8; ++i)                      \
    BUF[rt][i] = (_b + g * 8 + i < NF) ? xp[rt][_b + i] : 0.f; }

#define DOC(BUF, CC) { bf16x8 _w = wp[(size_t)(CC) * 64];            \
  _Pragma("unroll") for (int rt = 0; rt < 2; ++rt) { bf16x8 _a;      \
    _Pragma("unroll") for (int i = 0; i < 8; ++i)                    \
      _a[i] = (short)f2bf(BUF[rt][i]);                               \
    acc[rt] = __builtin_amdgcn_mfma_f32_16x16x32_bf16(_a, _w, acc[rt], 0, 0, 0); } }

  LOADC(xA, 0);
  LOADC(xB, 1);
  int c = 0;
  for (; c + 4 < NCH; c += 2) {
    DOC(xA, c);     LOADC(xA, c + 2);
    DOC(xB, c + 1); LOADC(xB, c + 3);
  }
  // c == NCH-3 (odd NCH): chunks c, c+1, c+2 remain; c+2 is the guarded tail
  DOC(xA, c);     LOADCG(xA, c + 2);
  DOC(xB, c + 1);
  DOC(xA, c + 2);
#undef LOADC
#undef LOADCG
#undef DOC

  // D layout (m89): col = lane&15, row_in_tile = (lane>>4)*4 + reg
#pragma unroll
  for (int rt = 0; rt < 2; ++rt)
#pragma unroll
    for (int r = 0; r < 4; ++r) {
      int row = row0 + rt * 16 + g * 4 + r;
      if (row < n) hs1[(size_t)row * NH + rl] = f2bf(acc[rt][r] * dis[row]);
    }
}

// ---------------- pull layer 1 + bias + relu + GEMM2 fused (16 lanes/node) --
// bit0 = column half (16B), bits1-3 = edge phase (mod 8).
__global__ __launch_bounds__(256) void k_pull1(
    const int* __restrict__ off, const int* __restrict__ srcs,
    const float* __restrict__ dis, const uint4* __restrict__ hs1,
    const float* __restrict__ b1, const float* __restrict__ W2,
    uint4* __restrict__ hs2, int n) {
  int t = blockIdx.x * blockDim.x + threadIdx.x;
  int d = t >> 4;
  if (d >= n) return;
  int sub = t & 15, half = sub & 1, ph = sub >> 1;  // ph in [0,8)

  float a[8] = {0.f, 0.f, 0.f, 0.f, 0.f, 0.f, 0.f, 0.f};
  if (ph == 0) acc8(a, hs1[(size_t)d * 2 + half]);  // self loop, once per half

  int k = off[d] + ph, k1 = off[d + 1];
  for (; k + 8 < k1; k += 16) {  // 2 independent gathers in flight
    int s0 = srcs[k], s1 = srcs[k + 8];
    uint4 r0 = hs1[(size_t)s0 * 2 + half];
    uint4 r1 = hs1[(size_t)s1 * 2 + half];
    acc8(a, r0);
    acc8(a, r1);
  }
  if (k < k1) acc8(a, hs1[(size_t)srcs[k] * 2 + half]);

#pragma unroll
  for (int i = 0; i < 8; ++i) {  // reduce over the 8 phases (lane bits 1..3)
    a[i] += __shfl_xor(a[i], 2);
    a[i] += __shfl_xor(a[i], 4);
    a[i] += __shfl_xor(a[i], 8);
  }

  // fused epilogue: v = relu(a*dis + b1), p = v @ W2 (half each), combine
  float dd = dis[d];
  float v[8];
#pragma unroll
  for (int i = 0; i < 8; ++i) v[i] = fmaxf(a[i] * dd + b1[half * 8 + i], 0.f);
  float p[NC];
#pragma unroll
  for (int c = 0; c < NC; ++c) {
    float s = 0.f;
#pragma unroll
    for (int i = 0; i < 8; ++i) s = fmaf(v[i], W2[(half * 8 + i) * NC + c], s);
    p[c] = s;
  }
#pragma unroll
  for (int c = 0; c < NC; ++c) p[c] += __shfl_xor(p[c], 1);  // combine halves
  if (sub == 0) {
    uint4 o;
    o.x = packbf(p[0] * dd, p[1] * dd);
    o.y = packbf(p[2] * dd, p[3] * dd);
    o.z = packbf(p[4] * dd, p[5] * dd);
    o.w = packbf(p[6] * dd, 0.f);  // pad col
    hs2[d] = o;
  }
}

// ---------------- pull layer 2 + bias + relu + log_softmax (8 lanes/node) ---
__global__ __launch_bounds__(256) void k_pull2(
    const int* __restrict__ off, const int* __restrict__ srcs,
    const float* __restrict__ dis, const uint4* __restrict__ hs2,
    const float* __restrict__ b2, float* __restrict__ out, int n) {
  int t = blockIdx.x * blockDim.x + threadIdx.x;
  int d = t >> 3;
  if (d >= n) return;
  int ph = t & 7;

  float a[8] = {0.f, 0.f, 0.f, 0.f, 0.f, 0.f, 0.f, 0.f};
  if (ph == 0) acc8(a, hs2[d]);  // self loop once

  int k = off[d] + ph, k1 = off[d + 1];
  for (; k + 8 < k1; k += 16) {
    int s0 = srcs[k], s1 = srcs[k + 8];
    uint4 r0 = hs2[s0];
    uint4 r1 = hs2[s1];
    acc8(a, r0);
    acc8(a, r1);
  }
  if (k < k1) acc8(a, hs2[srcs[k]]);

#pragma unroll
  for (int i = 0; i < 8; ++i) {  // reduce across the 8 phase lanes
    a[i] += __shfl_xor(a[i], 1);
    a[i] += __shfl_xor(a[i], 2);
    a[i] += __shfl_xor(a[i], 4);
  }
  float dd = dis[d];
  float u[NC];
#pragma unroll
  for (int c = 0; c < NC; ++c) u[c] = fmaxf(a[c] * dd + b2[c], 0.f);
  float m = u[0];
#pragma unroll
  for (int c = 1; c < NC; ++c) m = fmaxf(m, u[c]);
  float sum = 0.f;
#pragma unroll
  for (int c = 0; c < NC; ++c) sum += expf(u[c] - m);
  float lg = logf(sum);
  if (ph < NC) out[(size_t)d * NC + ph] = u[ph] - m - lg;
}

extern "C" void kernel_launch(void* const* d_in, const int* in_sizes, int n_in,
                              void* d_out, int out_size, void* d_ws, size_t ws_size,
                              hipStream_t stream) {
  const float* x  = (const float*)d_in[0];
  const int*   ei = (const int*)d_in[1];
  const float* W1 = (const float*)d_in[2];
  const float* b1 = (const float*)d_in[3];
  const float* W2 = (const float*)d_in[4];
  const float* b2 = (const float*)d_in[5];
  int n = in_sizes[0] / NF;   // 100000
  int E = in_sizes[1] / 2;    // 3200000
  int nbkt = (n + 255) >> 8;  // 391

  // workspace layout (each region 16B-aligned)
  char* w = (char*)d_ws;
#define TAKE(ptrty, name, bytes) \
  ptrty name = (ptrty)w; w += ((size_t)(bytes) + 15) & ~(size_t)15;
  TAKE(unsigned short*, hs1,  sizeof(short) * (size_t)n * NH)
  TAKE(uint4*,          hs2,  16 * (size_t)n)
  TAKE(float*,          dis,  sizeof(float) * n)
  TAKE(short*,          Wb,   sizeof(short) * NCH * 64 * 8)
  TAKE(int*,            bcnt, sizeof(int) * 16 * NBKT_MAX)
  TAKE(int*,            bfill,sizeof(int) * 16 * NBKT_MAX)
  TAKE(int*,            bbase,sizeof(int) * (NBKT_MAX + 1))
  TAKE(int*,            ebuf, sizeof(int) * (size_t)E)
  TAKE(int*,            off,  sizeof(int) * (n + 1))
  TAKE(int*,            srcs, sizeof(int) * (size_t)E)
#undef TAKE
  float* out = (float*)d_out;

  int nsb = (E + SC_C - 1) / SC_C;  // 1042

  // independent prep (also zeroes bcnt)
  k_wpack_zero<<<(NCH * 64 * 8 + 255) / 256, 256, 0, stream>>>(W1, Wb, bcnt);

  // bucketed CSR build
  k_bcount<<<nsb, 256, 0, stream>>>(ei + E, bcnt, E, nbkt);
  k_bscan<<<1, NBKT_MAX, 0, stream>>>(bcnt, bbase, bfill, nbkt);
  k_bscatter<<<nsb, 256, 0, stream>>>(ei, bfill, ebuf, E, nbkt);
  k_bcsr<<<nbkt, 256, 0, stream>>>(ebuf, bbase, off, srcs, dis, n);

  // features
  k_gemm1<<<(n + 63) / 64, 128, 0, stream>>>(x, Wb, dis, hs1, n);
  k_pull1<<<((size_t)n * 16 + 255) / 256, 256, 0, stream>>>(
      off, srcs, dis, (const uint4*)hs1, b1, W2, hs2, n);
  k_pull2<<<((size_t)n * 8 + 255) / 256, 256, 0, stream>>>(
      off, srcs, dis, hs2, b2, out, n);
}